// Round 6
// baseline (215.258 us; speedup 1.0000x reference)
//
#include <hip/hip_runtime.h>

#define N_NODES 40000
#define N_EDGES 640000
#define HD 128
#define N_REL2 474
#define BN_EPS 1e-5f
#define NB_SCAN ((N_NODES + 255) / 256)  // 157 scan blocks

// K1: histogram of edge destinations
__global__ __launch_bounds__(256) void k_hist(
        const int* __restrict__ dst, int* __restrict__ counts) {
    int e = blockIdx.x * 256 + threadIdx.x;
    if (e < N_EDGES) atomicAdd(counts + dst[e], 1);
}

// K2a: per-block sum of 256 counts
__global__ __launch_bounds__(256) void k_scan_part(
        const int* __restrict__ counts, int* __restrict__ bsum) {
    __shared__ int ls[256];
    int t = threadIdx.x;
    int idx = blockIdx.x * 256 + t;
    ls[t] = (idx < N_NODES) ? counts[idx] : 0;
    __syncthreads();
    #pragma unroll
    for (int off = 128; off > 0; off >>= 1) {
        if (t < off) ls[t] += ls[t + off];
        __syncthreads();
    }
    if (t == 0) bsum[blockIdx.x] = ls[0];
}

// K2b: per-block local scan; block offset from replicated top-level scan of bsum
__global__ __launch_bounds__(256) void k_scan_down(
        const int* __restrict__ counts, const int* __restrict__ bsum,
        int* __restrict__ row_off, int* __restrict__ cursor) {
    __shared__ int btop[256];
    __shared__ int ls[256];
    int t = threadIdx.x;
    btop[t] = (t < NB_SCAN) ? bsum[t] : 0;
    __syncthreads();
    #pragma unroll
    for (int off = 1; off < 256; off <<= 1) {
        int tmp = (t >= off) ? btop[t - off] : 0;
        __syncthreads();
        btop[t] += tmp;
        __syncthreads();
    }
    int blockoff = (blockIdx.x == 0) ? 0 : btop[blockIdx.x - 1];
    int idx = blockIdx.x * 256 + t;
    int v = (idx < N_NODES) ? counts[idx] : 0;
    ls[t] = v;
    __syncthreads();
    #pragma unroll
    for (int off = 1; off < 256; off <<= 1) {
        int tmp = (t >= off) ? ls[t - off] : 0;
        __syncthreads();
        ls[t] += tmp;
        __syncthreads();
    }
    int excl = ls[t] - v + blockoff;
    if (idx < N_NODES) {
        row_off[idx] = excl;
        cursor[idx] = excl;
    }
    if (idx == N_NODES) row_off[N_NODES] = N_EDGES;
}

// K3: scatter rel ids into CSR order (order within a node irrelevant)
__global__ __launch_bounds__(256) void k_sortrel(
        const int* __restrict__ dst, const int* __restrict__ rel_id,
        int* __restrict__ cursor, int* __restrict__ sorted_rel) {
    int e = blockIdx.x * 256 + threadIdx.x;
    if (e < N_EDGES) {
        int p = atomicAdd(cursor + dst[e], 1);
        sorted_rel[p] = rel_id[e];
    }
}

// K4: RW = rel_emb @ neigh_w  (474 x 128 @ 128 x 128)
__global__ __launch_bounds__(128) void k_rw(
        const float* __restrict__ R, const float* __restrict__ W,
        float* __restrict__ RW) {
    __shared__ float row[HD];
    int r = blockIdx.x, c = threadIdx.x;
    row[c] = R[(size_t)r * HD + c];
    __syncthreads();
    float acc = 0.f;
    #pragma unroll 8
    for (int k = 0; k < HD; ++k) acc += row[k] * W[(size_t)k * HD + c];
    RW[(size_t)r * HD + c] = acc;
}

// K5 (fused): one wave per node — dots (lane-private serial over R row),
// per-node shfl max/denom, online-softmax chunks, weighted RW accumulation.
__global__ __launch_bounds__(256) void k_fused(
        const float* __restrict__ ent_emb, const float* __restrict__ R,
        const float* __restrict__ RW, const int* __restrict__ row_off,
        const int* __restrict__ sorted_rel, float* __restrict__ h) {
    __shared__ __align__(16) float ent_s[4][HD];
    int wave = threadIdx.x >> 6;
    int lane = threadIdx.x & 63;
    int n = blockIdx.x * 4 + wave;
    // stage this node's ent row in LDS (wave-private slot, wave-synchronous)
    float2 e2 = ((const float2*)(ent_emb + (size_t)n * HD))[lane];
    ((float2*)ent_s[wave])[lane] = e2;
    int beg = row_off[n], end = row_off[n + 1];
    float l = 0.f, mrun = -INFINITY;
    float2 acc = make_float2(0.f, 0.f);
    const float4* es = (const float4*)ent_s[wave];
    for (int base = beg; base < end; base += 64) {
        int i = base + lane;
        int cnt = min(64, end - base);
        bool act = (i < end);
        int r = act ? sorted_rel[i] : 0;
        float dot = -INFINITY;
        if (act) {
            const float4* rr = (const float4*)(R + (size_t)r * HD);
            float d = 0.f;
            #pragma unroll 8
            for (int k = 0; k < 32; ++k) {
                float4 a = rr[k];
                float4 b = es[k];
                d += a.x * b.x + a.y * b.y + a.z * b.z + a.w * b.w;
            }
            dot = d;
        }
        // chunk max (once per chunk, not per edge)
        float m = dot;
        #pragma unroll
        for (int msk = 32; msk >= 1; msk >>= 1)
            m = fmaxf(m, __shfl_xor(m, msk, 64));
        if (m > mrun) {  // wave-uniform online rescale
            float sc = __expf(mrun - m);  // first chunk: exp(-inf)=0
            l *= sc;
            acc.x *= sc;
            acc.y *= sc;
            mrun = m;
        }
        float p = act ? __expf(dot - mrun) : 0.f;
        l += p;
        for (int j = 0; j < cnt; ++j) {
            float pj = __shfl(p, j, 64);
            int rj = __shfl(r, j, 64);
            float2 wv = ((const float2*)(RW + (size_t)rj * HD))[lane];
            acc.x += pj * wv.x;
            acc.y += pj * wv.y;
        }
    }
    #pragma unroll
    for (int msk = 32; msk >= 1; msk >>= 1) l += __shfl_xor(l, msk, 64);
    float invl = (l > 0.f) ? 1.f / l : 0.f;
    ((float2*)(h + (size_t)n * HD))[lane] = make_float2(acc.x * invl, acc.y * invl);
}

// K6: per-column sum / sumsq over rows (block-partial -> global atomics)
__global__ __launch_bounds__(256) void k_stats(
        const float* __restrict__ Hout, float* __restrict__ colsum,
        float* __restrict__ colsumsq) {
    __shared__ float ls[256], lq[256];
    int t = threadIdx.x;
    int c = t & 127, half = t >> 7;
    int rbase = blockIdx.x * 64;
    float sum = 0.f, sq = 0.f;
    #pragma unroll 4
    for (int i = 0; i < 32; ++i) {
        int r = rbase + half + i * 2;
        float v = Hout[(size_t)r * HD + c];
        sum += v;
        sq += v * v;
    }
    ls[t] = sum;
    lq[t] = sq;
    __syncthreads();
    if (t < 128) {
        sum = ls[t] + ls[t + 128];
        sq = lq[t] + lq[t + 128];
        atomicAdd(colsum + c, sum);
        atomicAdd(colsumsq + c, sq);
    }
}

// K7: out = tanh((h - mean) * rstd * gamma + beta), in place on d_out
__global__ __launch_bounds__(256) void k_apply(
        float* __restrict__ Hout, const float* __restrict__ colsum,
        const float* __restrict__ colsumsq, const float* __restrict__ gamma,
        const float* __restrict__ beta) {
    int idx = blockIdx.x * 256 + threadIdx.x;  // float4 index
    if (idx >= N_NODES * HD / 4) return;
    int c0 = (idx * 4) & 127;
    float4 hv4 = ((const float4*)Hout)[idx];
    const float inv = 1.f / (float)N_NODES;
    float hv[4] = {hv4.x, hv4.y, hv4.z, hv4.w};
    float o[4];
    #pragma unroll
    for (int j = 0; j < 4; ++j) {
        int c = c0 + j;
        float mean = colsum[c] * inv;
        float var = colsumsq[c] * inv - mean * mean;
        float rstd = rsqrtf(var + BN_EPS);
        o[j] = tanhf((hv[j] - mean) * rstd * gamma[c] + beta[c]);
    }
    ((float4*)Hout)[idx] = make_float4(o[0], o[1], o[2], o[3]);
}

extern "C" void kernel_launch(void* const* d_in, const int* in_sizes, int n_in,
                              void* d_out, int out_size, void* d_ws, size_t ws_size,
                              hipStream_t stream) {
    const float* ent_emb  = (const float*)d_in[0];
    const float* rel_emb  = (const float*)d_in[1];
    const float* neigh_w  = (const float*)d_in[2];
    const float* bn_gamma = (const float*)d_in[3];
    const float* bn_beta  = (const float*)d_in[4];
    const int*   rel_id   = (const int*)d_in[5];
    const int*   dst      = (const int*)d_in[6];
    float* out = (float*)d_out;

    // workspace layout (4-byte units) — first 40256 words are memset to 0
    int*      counts     = (int*)d_ws;                    // [40000]
    float*    colsum     = (float*)d_ws + 40000;          // [128]
    float*    colsumsq   = (float*)d_ws + 40128;          // [128]
    int*      row_off    = (int*)d_ws + 40256;            // [40001]
    int*      cursor     = (int*)d_ws + 80257;            // [40000]
    int*      sorted_rel = (int*)d_ws + 120257;           // [640000]
    float*    RW         = (float*)d_ws + 760257;         // [474*128]
    int*      bsum       = (int*)d_ws + 760257 + N_REL2 * HD;  // [NB_SCAN]

    hipMemsetAsync(d_ws, 0, (size_t)40256 * 4, stream);

    k_hist<<<(N_EDGES + 255) / 256, 256, 0, stream>>>(dst, counts);
    k_scan_part<<<NB_SCAN, 256, 0, stream>>>(counts, bsum);
    k_scan_down<<<NB_SCAN, 256, 0, stream>>>(counts, bsum, row_off, cursor);
    k_sortrel<<<(N_EDGES + 255) / 256, 256, 0, stream>>>(dst, rel_id, cursor, sorted_rel);
    k_rw<<<N_REL2, 128, 0, stream>>>(rel_emb, neigh_w, RW);
    k_fused<<<N_NODES / 4, 256, 0, stream>>>(ent_emb, rel_emb, RW, row_off, sorted_rel, out);
    k_stats<<<N_NODES / 64, 256, 0, stream>>>(out, colsum, colsumsq);
    k_apply<<<N_NODES * HD / 4 / 256, 256, 0, stream>>>(out, colsum, colsumsq, bn_gamma, bn_beta);
}

// Round 7
// 194.626 us; speedup vs baseline: 1.1060x; 1.1060x over previous
//
#include <hip/hip_runtime.h>

#define N_NODES 40000
#define N_EDGES 640000
#define HD 128
#define N_REL2 474
#define BN_EPS 1e-5f
#define NB_SCAN ((N_NODES + 255) / 256)  // 157 scan blocks

// K1: histogram of edge destinations
__global__ __launch_bounds__(256) void k_hist(
        const int* __restrict__ dst, int* __restrict__ counts) {
    int e = blockIdx.x * 256 + threadIdx.x;
    if (e < N_EDGES) atomicAdd(counts + dst[e], 1);
}

// K2a: per-block sum of 256 counts
__global__ __launch_bounds__(256) void k_scan_part(
        const int* __restrict__ counts, int* __restrict__ bsum) {
    __shared__ int ls[256];
    int t = threadIdx.x;
    int idx = blockIdx.x * 256 + t;
    ls[t] = (idx < N_NODES) ? counts[idx] : 0;
    __syncthreads();
    #pragma unroll
    for (int off = 128; off > 0; off >>= 1) {
        if (t < off) ls[t] += ls[t + off];
        __syncthreads();
    }
    if (t == 0) bsum[blockIdx.x] = ls[0];
}

// K2b: per-block local scan; block offset from replicated top-level scan of bsum
__global__ __launch_bounds__(256) void k_scan_down(
        const int* __restrict__ counts, const int* __restrict__ bsum,
        int* __restrict__ row_off, int* __restrict__ cursor) {
    __shared__ int btop[256];
    __shared__ int ls[256];
    int t = threadIdx.x;
    btop[t] = (t < NB_SCAN) ? bsum[t] : 0;
    __syncthreads();
    #pragma unroll
    for (int off = 1; off < 256; off <<= 1) {
        int tmp = (t >= off) ? btop[t - off] : 0;
        __syncthreads();
        btop[t] += tmp;
        __syncthreads();
    }
    int blockoff = (blockIdx.x == 0) ? 0 : btop[blockIdx.x - 1];
    int idx = blockIdx.x * 256 + t;
    int v = (idx < N_NODES) ? counts[idx] : 0;
    ls[t] = v;
    __syncthreads();
    #pragma unroll
    for (int off = 1; off < 256; off <<= 1) {
        int tmp = (t >= off) ? ls[t - off] : 0;
        __syncthreads();
        ls[t] += tmp;
        __syncthreads();
    }
    int excl = ls[t] - v + blockoff;
    if (idx < N_NODES) {
        row_off[idx] = excl;
        cursor[idx] = excl;
    }
    if (idx == N_NODES) row_off[N_NODES] = N_EDGES;
}

// K3: scatter rel ids into CSR order (order within a node irrelevant)
__global__ __launch_bounds__(256) void k_sortrel(
        const int* __restrict__ dst, const int* __restrict__ rel_id,
        int* __restrict__ cursor, int* __restrict__ sorted_rel) {
    int e = blockIdx.x * 256 + threadIdx.x;
    if (e < N_EDGES) {
        int p = atomicAdd(cursor + dst[e], 1);
        sorted_rel[p] = rel_id[e];
    }
}

// K4: RW = rel_emb @ neigh_w  (474 x 128 @ 128 x 128)
__global__ __launch_bounds__(128) void k_rw(
        const float* __restrict__ R, const float* __restrict__ W,
        float* __restrict__ RW) {
    __shared__ float row[HD];
    int r = blockIdx.x, c = threadIdx.x;
    row[c] = R[(size_t)r * HD + c];
    __syncthreads();
    float acc = 0.f;
    #pragma unroll 8
    for (int k = 0; k < HD; ++k) acc += row[k] * W[(size_t)k * HD + c];
    RW[(size_t)r * HD + c] = acc;
}

// K5 (fused, quad-per-edge): one wave per node.
//   - chunk of 16 edges: quad (4 lanes) computes one edge's 128-dot
//     (8 indep float4 loads vs LDS ent) + 2-step quad shfl reduce
//   - chunk max: 4 more shfl_xor steps (registers only)
//   - online rescale (wave-uniform), quad leader writes packed (p, r) to LDS
//   - accumulate: per edge one ds_read_b64 broadcast + coalesced RW gather
__global__ __launch_bounds__(256) void k_fused(
        const float* __restrict__ ent_emb, const float* __restrict__ R,
        const float* __restrict__ RW, const int* __restrict__ row_off,
        const int* __restrict__ sorted_rel, float* __restrict__ h) {
    __shared__ __align__(16) float ent_s[4][HD];
    __shared__ __align__(8) float2 pr[4][16];  // (p, bitcast r) per chunk edge
    int wave = threadIdx.x >> 6;
    int lane = threadIdx.x & 63;
    int n = blockIdx.x * 4 + wave;
    // stage this node's ent row in LDS (wave-private slot, wave-synchronous)
    float2 e2 = ((const float2*)(ent_emb + (size_t)n * HD))[lane];
    ((float2*)ent_s[wave])[lane] = e2;
    int beg = row_off[n], end = row_off[n + 1];
    int q = lane >> 2, sub = lane & 3;
    float l = 0.f, mrun = -INFINITY;
    float2 acc = make_float2(0.f, 0.f);
    const float4* es = (const float4*)ent_s[wave];
    for (int base = beg; base < end; base += 16) {
        int cnt = min(16, end - base);
        float s_e = -INFINITY;
        int r = 0;
        if (q < cnt) {
            r = sorted_rel[base + q];  // same addr across quad -> broadcast
            const float4* rr = (const float4*)(R + (size_t)r * HD);
            float d = 0.f;
            #pragma unroll
            for (int k = 0; k < 8; ++k) {
                float4 a = rr[sub * 8 + k];
                float4 b = es[sub * 8 + k];
                d += a.x * b.x + a.y * b.y + a.z * b.z + a.w * b.w;
            }
            d += __shfl_xor(d, 1, 64);
            d += __shfl_xor(d, 2, 64);
            s_e = d;  // all 4 lanes of quad hold the dot
        }
        // chunk max across the 16 quads (registers only)
        float m = s_e;
        #pragma unroll
        for (int msk = 4; msk <= 32; msk <<= 1)
            m = fmaxf(m, __shfl_xor(m, msk, 64));
        if (m > mrun) {  // wave-uniform online rescale
            float sc = __expf(mrun - m);  // first chunk: exp(-inf)=0
            l *= sc;
            acc.x *= sc;
            acc.y *= sc;
            mrun = m;
        }
        if (q < cnt && sub == 0)
            pr[wave][q] = make_float2(__expf(s_e - mrun), __int_as_float(r));
        // accumulate: one b64 LDS broadcast per edge, no shuffles
        for (int j = 0; j < cnt; ++j) {
            float2 v = pr[wave][j];
            float pj = v.x;
            int rj = __float_as_int(v.y);
            float2 wv = ((const float2*)(RW + (size_t)rj * HD))[lane];
            l += pj;  // uniform across lanes
            acc.x += pj * wv.x;
            acc.y += pj * wv.y;
        }
    }
    float invl = (l > 0.f) ? 1.f / l : 0.f;
    ((float2*)(h + (size_t)n * HD))[lane] = make_float2(acc.x * invl, acc.y * invl);
}

// K6: per-column sum / sumsq over rows (block-partial -> global atomics)
__global__ __launch_bounds__(256) void k_stats(
        const float* __restrict__ Hout, float* __restrict__ colsum,
        float* __restrict__ colsumsq) {
    __shared__ float ls[256], lq[256];
    int t = threadIdx.x;
    int c = t & 127, half = t >> 7;
    int rbase = blockIdx.x * 64;
    float sum = 0.f, sq = 0.f;
    #pragma unroll 4
    for (int i = 0; i < 32; ++i) {
        int r = rbase + half + i * 2;
        float v = Hout[(size_t)r * HD + c];
        sum += v;
        sq += v * v;
    }
    ls[t] = sum;
    lq[t] = sq;
    __syncthreads();
    if (t < 128) {
        sum = ls[t] + ls[t + 128];
        sq = lq[t] + lq[t + 128];
        atomicAdd(colsum + c, sum);
        atomicAdd(colsumsq + c, sq);
    }
}

// K7: out = tanh((h - mean) * rstd * gamma + beta), in place on d_out
__global__ __launch_bounds__(256) void k_apply(
        float* __restrict__ Hout, const float* __restrict__ colsum,
        const float* __restrict__ colsumsq, const float* __restrict__ gamma,
        const float* __restrict__ beta) {
    int idx = blockIdx.x * 256 + threadIdx.x;  // float4 index
    if (idx >= N_NODES * HD / 4) return;
    int c0 = (idx * 4) & 127;
    float4 hv4 = ((const float4*)Hout)[idx];
    const float inv = 1.f / (float)N_NODES;
    float hv[4] = {hv4.x, hv4.y, hv4.z, hv4.w};
    float o[4];
    #pragma unroll
    for (int j = 0; j < 4; ++j) {
        int c = c0 + j;
        float mean = colsum[c] * inv;
        float var = colsumsq[c] * inv - mean * mean;
        float rstd = rsqrtf(var + BN_EPS);
        o[j] = tanhf((hv[j] - mean) * rstd * gamma[c] + beta[c]);
    }
    ((float4*)Hout)[idx] = make_float4(o[0], o[1], o[2], o[3]);
}

extern "C" void kernel_launch(void* const* d_in, const int* in_sizes, int n_in,
                              void* d_out, int out_size, void* d_ws, size_t ws_size,
                              hipStream_t stream) {
    const float* ent_emb  = (const float*)d_in[0];
    const float* rel_emb  = (const float*)d_in[1];
    const float* neigh_w  = (const float*)d_in[2];
    const float* bn_gamma = (const float*)d_in[3];
    const float* bn_beta  = (const float*)d_in[4];
    const int*   rel_id   = (const int*)d_in[5];
    const int*   dst      = (const int*)d_in[6];
    float* out = (float*)d_out;

    // workspace layout (4-byte units) — first 40256 words are memset to 0
    int*      counts     = (int*)d_ws;                    // [40000]
    float*    colsum     = (float*)d_ws + 40000;          // [128]
    float*    colsumsq   = (float*)d_ws + 40128;          // [128]
    int*      row_off    = (int*)d_ws + 40256;            // [40001]
    int*      cursor     = (int*)d_ws + 80257;            // [40000]
    int*      sorted_rel = (int*)d_ws + 120257;           // [640000]
    float*    RW         = (float*)d_ws + 760257;         // [474*128]
    int*      bsum       = (int*)d_ws + 760257 + N_REL2 * HD;  // [NB_SCAN]

    hipMemsetAsync(d_ws, 0, (size_t)40256 * 4, stream);

    k_hist<<<(N_EDGES + 255) / 256, 256, 0, stream>>>(dst, counts);
    k_scan_part<<<NB_SCAN, 256, 0, stream>>>(counts, bsum);
    k_scan_down<<<NB_SCAN, 256, 0, stream>>>(counts, bsum, row_off, cursor);
    k_sortrel<<<(N_EDGES + 255) / 256, 256, 0, stream>>>(dst, rel_id, cursor, sorted_rel);
    k_rw<<<N_REL2, 128, 0, stream>>>(rel_emb, neigh_w, RW);
    k_fused<<<N_NODES / 4, 256, 0, stream>>>(ent_emb, rel_emb, RW, row_off, sorted_rel, out);
    k_stats<<<N_NODES / 64, 256, 0, stream>>>(out, colsum, colsumsq);
    k_apply<<<N_NODES * HD / 4 / 256, 256, 0, stream>>>(out, colsum, colsumsq, bn_gamma, bn_beta);
}

// Round 8
// 157.365 us; speedup vs baseline: 1.3679x; 1.2368x over previous
//
#include <hip/hip_runtime.h>

#define N_NODES 40000
#define N_EDGES 640000
#define HD 128
#define N_REL2 474
#define BN_EPS 1e-5f
#define NB_SCAN ((N_NODES + 255) / 256)  // 157 scan blocks

// K1: histogram of edge destinations
__global__ __launch_bounds__(256) void k_hist(
        const int* __restrict__ dst, int* __restrict__ counts) {
    int e = blockIdx.x * 256 + threadIdx.x;
    if (e < N_EDGES) atomicAdd(counts + dst[e], 1);
}

// K2a: per-block sum of 256 counts
__global__ __launch_bounds__(256) void k_scan_part(
        const int* __restrict__ counts, int* __restrict__ bsum) {
    __shared__ int ls[256];
    int t = threadIdx.x;
    int idx = blockIdx.x * 256 + t;
    ls[t] = (idx < N_NODES) ? counts[idx] : 0;
    __syncthreads();
    #pragma unroll
    for (int off = 128; off > 0; off >>= 1) {
        if (t < off) ls[t] += ls[t + off];
        __syncthreads();
    }
    if (t == 0) bsum[blockIdx.x] = ls[0];
}

// K2b: per-block local scan; block offset from replicated top-level scan of bsum
__global__ __launch_bounds__(256) void k_scan_down(
        const int* __restrict__ counts, const int* __restrict__ bsum,
        int* __restrict__ row_off, int* __restrict__ cursor) {
    __shared__ int btop[256];
    __shared__ int ls[256];
    int t = threadIdx.x;
    btop[t] = (t < NB_SCAN) ? bsum[t] : 0;
    __syncthreads();
    #pragma unroll
    for (int off = 1; off < 256; off <<= 1) {
        int tmp = (t >= off) ? btop[t - off] : 0;
        __syncthreads();
        btop[t] += tmp;
        __syncthreads();
    }
    int blockoff = (blockIdx.x == 0) ? 0 : btop[blockIdx.x - 1];
    int idx = blockIdx.x * 256 + t;
    int v = (idx < N_NODES) ? counts[idx] : 0;
    ls[t] = v;
    __syncthreads();
    #pragma unroll
    for (int off = 1; off < 256; off <<= 1) {
        int tmp = (t >= off) ? ls[t - off] : 0;
        __syncthreads();
        ls[t] += tmp;
        __syncthreads();
    }
    int excl = ls[t] - v + blockoff;
    if (idx < N_NODES) {
        row_off[idx] = excl;
        cursor[idx] = excl;
    }
    if (idx == N_NODES) row_off[N_NODES] = N_EDGES;
}

// K3 (fused dot+exp+CSR-scatter): 16 lanes per edge.
//   p = exp(dot(R[rel], ent[dst]))  [no max subtraction: |dot| < ~60 << 88]
//   scatter packed (p, rel) to claimed CSR slot.
__global__ __launch_bounds__(256) void k_edge_sort(
        const float* __restrict__ ent_emb, const float* __restrict__ R,
        const int* __restrict__ rel_id, const int* __restrict__ dst,
        int* __restrict__ cursor, float2* __restrict__ sorted_pr) {
    int t = threadIdx.x;
    int e = blockIdx.x * 16 + (t >> 4);
    if (e >= N_EDGES) return;
    int lam = t & 15;
    int r = rel_id[e], d = dst[e];
    const float4* rr = (const float4*)(R + (size_t)r * HD);
    const float4* ee = (const float4*)(ent_emb + (size_t)d * HD);
    float4 a0 = rr[lam * 2], a1 = rr[lam * 2 + 1];
    float4 b0 = ee[lam * 2], b1 = ee[lam * 2 + 1];
    float s = a0.x * b0.x + a0.y * b0.y + a0.z * b0.z + a0.w * b0.w
            + a1.x * b1.x + a1.y * b1.y + a1.z * b1.z + a1.w * b1.w;
    #pragma unroll
    for (int m = 8; m >= 1; m >>= 1) s += __shfl_xor(s, m, 64);  // within 16-group
    if (lam == 0) {
        float p = __expf(s);
        int pos = atomicAdd(cursor + d, 1);
        sorted_pr[pos] = make_float2(p, __int_as_float(r));
    }
}

// K4: RW = rel_emb @ neigh_w  (474 x 128 @ 128 x 128)
__global__ __launch_bounds__(128) void k_rw(
        const float* __restrict__ R, const float* __restrict__ W,
        float* __restrict__ RW) {
    __shared__ float row[HD];
    int r = blockIdx.x, c = threadIdx.x;
    row[c] = R[(size_t)r * HD + c];
    __syncthreads();
    float acc = 0.f;
    #pragma unroll 8
    for (int k = 0; k < HD; ++k) acc += row[k] * W[(size_t)k * HD + c];
    RW[(size_t)r * HD + c] = acc;
}

// K5: pure gather-accumulate. One wave per node.
//   lane = (g, c4): g in 0..3 takes edges j%4==g; c4 in 0..15 owns cols [c4*8, c4*8+8)
//   4 independent RW gathers in flight per j-iteration; butterfly over g at end.
__global__ __launch_bounds__(256) void k_node_acc(
        const float* __restrict__ RW, const int* __restrict__ row_off,
        const float2* __restrict__ sorted_pr, float* __restrict__ h) {
    __shared__ __align__(8) float2 pr_s[4][64];
    int wave = threadIdx.x >> 6, lane = threadIdx.x & 63;
    int n = blockIdx.x * 4 + wave;
    if (n >= N_NODES) return;
    int beg = row_off[n], end = row_off[n + 1];
    int c4 = lane & 15, g = lane >> 4;
    float acc[8] = {};
    float lp = 0.f;
    const float4* RW4 = (const float4*)RW;
    for (int base = beg; base < end; base += 64) {
        int cnt = min(64, end - base);
        if (lane < cnt) pr_s[wave][lane] = sorted_pr[base + lane];
        // wave-synchronous LDS (in-order within wave; compiler inserts lgkmcnt)
        for (int j0 = 0; j0 < cnt; j0 += 4) {
            int eidx = j0 + g;
            if (eidx < cnt) {
                float2 v = pr_s[wave][eidx];
                float p = v.x;
                int r = __float_as_int(v.y);
                const float4* rowp = RW4 + (size_t)r * 32 + c4 * 2;
                float4 w0 = rowp[0], w1 = rowp[1];
                lp += p;
                acc[0] += p * w0.x; acc[1] += p * w0.y;
                acc[2] += p * w0.z; acc[3] += p * w0.w;
                acc[4] += p * w1.x; acc[5] += p * w1.y;
                acc[6] += p * w1.z; acc[7] += p * w1.w;
            }
        }
    }
    #pragma unroll
    for (int m = 16; m <= 32; m <<= 1) {
        lp += __shfl_xor(lp, m, 64);
        #pragma unroll
        for (int k = 0; k < 8; ++k) acc[k] += __shfl_xor(acc[k], m, 64);
    }
    float invl = (lp > 0.f) ? 1.f / lp : 0.f;
    if (g == 0) {
        float4* op = (float4*)(h + (size_t)n * HD + c4 * 8);
        op[0] = make_float4(acc[0] * invl, acc[1] * invl, acc[2] * invl, acc[3] * invl);
        op[1] = make_float4(acc[4] * invl, acc[5] * invl, acc[6] * invl, acc[7] * invl);
    }
}

// K6: per-column sum / sumsq over rows (block-partial -> global atomics)
__global__ __launch_bounds__(256) void k_stats(
        const float* __restrict__ Hout, float* __restrict__ colsum,
        float* __restrict__ colsumsq) {
    __shared__ float ls[256], lq[256];
    int t = threadIdx.x;
    int c = t & 127, half = t >> 7;
    int rbase = blockIdx.x * 64;
    float sum = 0.f, sq = 0.f;
    #pragma unroll 4
    for (int i = 0; i < 32; ++i) {
        int r = rbase + half + i * 2;
        float v = Hout[(size_t)r * HD + c];
        sum += v;
        sq += v * v;
    }
    ls[t] = sum;
    lq[t] = sq;
    __syncthreads();
    if (t < 128) {
        sum = ls[t] + ls[t + 128];
        sq = lq[t] + lq[t + 128];
        atomicAdd(colsum + c, sum);
        atomicAdd(colsumsq + c, sq);
    }
}

// K7: out = tanh((h - mean) * rstd * gamma + beta), in place; fast tanh via __expf
__global__ __launch_bounds__(256) void k_apply(
        float* __restrict__ Hout, const float* __restrict__ colsum,
        const float* __restrict__ colsumsq, const float* __restrict__ gamma,
        const float* __restrict__ beta) {
    int idx = blockIdx.x * 256 + threadIdx.x;  // float4 index
    if (idx >= N_NODES * HD / 4) return;
    int c0 = (idx * 4) & 127;
    float4 hv4 = ((const float4*)Hout)[idx];
    const float inv = 1.f / (float)N_NODES;
    float hv[4] = {hv4.x, hv4.y, hv4.z, hv4.w};
    float o[4];
    #pragma unroll
    for (int j = 0; j < 4; ++j) {
        int c = c0 + j;
        float mean = colsum[c] * inv;
        float var = colsumsq[c] * inv - mean * mean;
        float rstd = rsqrtf(var + BN_EPS);
        float x = (hv[j] - mean) * rstd * gamma[c] + beta[c];
        o[j] = 1.f - 2.f / (__expf(2.f * x) + 1.f);
    }
    ((float4*)Hout)[idx] = make_float4(o[0], o[1], o[2], o[3]);
}

extern "C" void kernel_launch(void* const* d_in, const int* in_sizes, int n_in,
                              void* d_out, int out_size, void* d_ws, size_t ws_size,
                              hipStream_t stream) {
    const float* ent_emb  = (const float*)d_in[0];
    const float* rel_emb  = (const float*)d_in[1];
    const float* neigh_w  = (const float*)d_in[2];
    const float* bn_gamma = (const float*)d_in[3];
    const float* bn_beta  = (const float*)d_in[4];
    const int*   rel_id   = (const int*)d_in[5];
    const int*   dst      = (const int*)d_in[6];
    float* out = (float*)d_out;

    // workspace layout (4-byte units) — first 40256 words are memset to 0
    int*      counts     = (int*)d_ws;                    // [40000]
    float*    colsum     = (float*)d_ws + 40000;          // [128]
    float*    colsumsq   = (float*)d_ws + 40128;          // [128]
    int*      row_off    = (int*)d_ws + 40256;            // [40001]
    int*      cursor     = (int*)d_ws + 80257;            // [40000]
    float2*   sorted_pr  = (float2*)((float*)d_ws + 120258);  // [640000] (8B aligned)
    float*    RW         = (float*)d_ws + 120258 + 2 * N_EDGES;  // [474*128]
    int*      bsum       = (int*)d_ws + 120258 + 2 * N_EDGES + N_REL2 * HD;  // [NB_SCAN]

    hipMemsetAsync(d_ws, 0, (size_t)40256 * 4, stream);

    k_hist<<<(N_EDGES + 255) / 256, 256, 0, stream>>>(dst, counts);
    k_scan_part<<<NB_SCAN, 256, 0, stream>>>(counts, bsum);
    k_scan_down<<<NB_SCAN, 256, 0, stream>>>(counts, bsum, row_off, cursor);
    k_edge_sort<<<N_EDGES / 16, 256, 0, stream>>>(ent_emb, rel_emb, rel_id, dst, cursor, sorted_pr);
    k_rw<<<N_REL2, 128, 0, stream>>>(rel_emb, neigh_w, RW);
    k_node_acc<<<N_NODES / 4, 256, 0, stream>>>(RW, row_off, sorted_pr, out);
    k_stats<<<N_NODES / 64, 256, 0, stream>>>(out, colsum, colsumsq);
    k_apply<<<N_NODES * HD / 4 / 256, 256, 0, stream>>>(out, colsum, colsumsq, bn_gamma, bn_beta);
}